// Round 1
// baseline (857.379 us; speedup 1.0000x reference)
//
#include <hip/hip_runtime.h>
#include <hip/hip_bf16.h>

typedef __attribute__((ext_vector_type(8))) short bf16x8;
typedef __attribute__((ext_vector_type(4))) float f32x4;
typedef __attribute__((ext_vector_type(4))) unsigned short u16x4;
typedef __attribute__((ext_vector_type(8))) unsigned short u16x8;

#define SEQ   4096
#define DIM   1024
#define MTOT  16384

static __device__ __forceinline__ unsigned short f2bf(float f) {
  union { float f; unsigned u; } v; v.f = f;
  unsigned r = v.u + 0x7FFFu + ((v.u >> 16) & 1u);
  return (unsigned short)(r >> 16);
}

static __device__ __forceinline__ unsigned short f2h(float f) {
  union { _Float16 h; unsigned short u; } v; v.h = (_Float16)f; return v.u;
}

static __device__ __forceinline__ float h2f(unsigned short u) {
  union { unsigned short u; _Float16 h; } v; v.u = u; return (float)v.h;
}

static __device__ __forceinline__ bf16x8 pack8(f32x4 a, f32x4 b) {
  bf16x8 v;
  v[0]=(short)f2bf(a[0]); v[1]=(short)f2bf(a[1]);
  v[2]=(short)f2bf(a[2]); v[3]=(short)f2bf(a[3]);
  v[4]=(short)f2bf(b[0]); v[5]=(short)f2bf(b[1]);
  v[6]=(short)f2bf(b[2]); v[7]=(short)f2bf(b[3]);
  return v;
}

// ---------------- fp32 -> bf16 preconvert (optionally scaled) ----------------
__global__ __launch_bounds__(256) void conv_bf16(
    const float* __restrict__ src, unsigned short* __restrict__ dst,
    int n8, float scale)
{
  const int i = blockIdx.x * 256 + threadIdx.x;
  if (i < n8) {
    const f32x4* s = (const f32x4*)(src + (size_t)i * 8);
    f32x4 a = s[0], b = s[1];
#pragma unroll
    for (int r = 0; r < 4; ++r) { a[r] *= scale; b[r] *= scale; }
    *(bf16x8*)(dst + (size_t)i * 8) = pack8(a, b);
  }
}

// ---------------- QKV GEMM, m97-style: 128x128 tile, global_load_lds w16 ----
// C = xb * Wz^T (both row-major over k). z=0 -> Q (Wq pre-scaled), z=1 -> K,
// z=2 -> Vt [b][e][s].
__global__ __launch_bounds__(256) void qkv_gemm2(
    const unsigned short* __restrict__ xb,
    const unsigned short* __restrict__ Wb,    // Wq|Wk|Wv bf16
    unsigned short* __restrict__ outQ)        // Q | K | Vt contiguous
{
  const int z = blockIdx.z;
  const unsigned short* __restrict__ Wz = Wb + (size_t)z * (DIM * DIM);
  unsigned short* __restrict__ outb = outQ + (size_t)z * ((size_t)MTOT * DIM);

  const int n0 = blockIdx.x * 128;
  const int m0 = blockIdx.y * 128;
  const int tid = threadIdx.x, ln = tid & 63, wv = tid >> 6;
  const int l15 = ln & 15, quad = ln >> 4;
  const int mw = wv >> 1, nw = wv & 1;
  const int lrow = ln >> 3, lcol = (ln & 7) * 8;

  __shared__ unsigned short Al[128 * 64];   // no padding: global_load_lds layout
  __shared__ unsigned short Bl[128 * 64];

  f32x4 acc[4][4] = {};

  for (int k0 = 0; k0 < DIM; k0 += 64) {
    __syncthreads();   // prior fragment reads done before DMA overwrites LDS
#pragma unroll
    for (int r = 0; r < 4; ++r) {
      const int rr = (wv * 4 + r) * 8 + lrow;
      const unsigned short* ga = xb + (size_t)(m0 + rr) * DIM + k0 + lcol;
      const unsigned short* gb = Wz + (size_t)(n0 + rr) * DIM + k0 + lcol;
      __builtin_amdgcn_global_load_lds(
          (const __attribute__((address_space(1))) void*)ga,
          (__attribute__((address_space(3))) void*)&Al[(wv * 4 + r) * 512], 16, 0, 0);
      __builtin_amdgcn_global_load_lds(
          (const __attribute__((address_space(1))) void*)gb,
          (__attribute__((address_space(3))) void*)&Bl[(wv * 4 + r) * 512], 16, 0, 0);
    }
    __syncthreads();   // vmcnt(0) drain: DMA complete, LDS valid
#pragma unroll
    for (int ks = 0; ks < 2; ++ks) {
      bf16x8 af[4], bfr[4];
#pragma unroll
      for (int i = 0; i < 4; ++i) {
        af[i]  = *(const bf16x8*)&Al[(mw * 64 + i * 16 + l15) * 64 + ks * 32 + quad * 8];
        bfr[i] = *(const bf16x8*)&Bl[(nw * 64 + i * 16 + l15) * 64 + ks * 32 + quad * 8];
      }
#pragma unroll
      for (int mi = 0; mi < 4; ++mi)
#pragma unroll
        for (int ni = 0; ni < 4; ++ni)
          acc[mi][ni] = __builtin_amdgcn_mfma_f32_16x16x32_bf16(af[mi], bfr[ni], acc[mi][ni], 0, 0, 0);
    }
  }

  if (z < 2) {
#pragma unroll
    for (int mi = 0; mi < 4; ++mi)
#pragma unroll
      for (int ni = 0; ni < 4; ++ni) {
        const int m = m0 + mw * 64 + mi * 16 + quad * 4;
        const int e = n0 + nw * 64 + ni * 16 + l15;
        unsigned short* p = outb + (size_t)m * DIM + e;
#pragma unroll
        for (int r = 0; r < 4; ++r) p[(size_t)r * DIM] = f2bf(acc[mi][ni][r]);
      }
  } else {
#pragma unroll
    for (int mi = 0; mi < 4; ++mi)
#pragma unroll
      for (int ni = 0; ni < 4; ++ni) {
        const int m = m0 + mw * 64 + mi * 16 + quad * 4;   // s index (4 consec)
        const int e = n0 + nw * 64 + ni * 16 + l15;
        const int bb = m >> 12, ss = m & 4095;
        u16x4 v4;
#pragma unroll
        for (int r = 0; r < 4; ++r) v4[r] = f2bf(acc[mi][ni][r]);
        *(u16x4*)(outb + ((size_t)bb * DIM + e) * SEQ + ss) = v4;
      }
  }
}

// ---------------- shared 128x128-tile GEMM mainloop (m97 structure) ---------
// C[128m x 128n] += A[m0.., k] * B[n0.., k]^T over k in [0, kmax).
// Abase/Bbase already offset to the tile's first row; lda/ldb in elements.
static __device__ __forceinline__ void mfma_tile128(
    const unsigned short* __restrict__ Abase, int lda,
    const unsigned short* __restrict__ Bbase, int ldb,
    int kmax, unsigned short* Al, unsigned short* Bl, f32x4 (&acc)[4][4])
{
  const int tid = threadIdx.x, ln = tid & 63, wv = tid >> 6;
  const int l15 = ln & 15, quad = ln >> 4;
  const int mw = wv >> 1, nw = wv & 1;
  const int lrow = ln >> 3, lcol = (ln & 7) * 8;

  for (int k0 = 0; k0 < kmax; k0 += 64) {
    __syncthreads();
#pragma unroll
    for (int r = 0; r < 4; ++r) {
      const int rr = (wv * 4 + r) * 8 + lrow;
      const unsigned short* ga = Abase + (size_t)rr * lda + k0 + lcol;
      const unsigned short* gb = Bbase + (size_t)rr * ldb + k0 + lcol;
      __builtin_amdgcn_global_load_lds(
          (const __attribute__((address_space(1))) void*)ga,
          (__attribute__((address_space(3))) void*)&Al[(wv * 4 + r) * 512], 16, 0, 0);
      __builtin_amdgcn_global_load_lds(
          (const __attribute__((address_space(1))) void*)gb,
          (__attribute__((address_space(3))) void*)&Bl[(wv * 4 + r) * 512], 16, 0, 0);
    }
    __syncthreads();
#pragma unroll
    for (int ks = 0; ks < 2; ++ks) {
      bf16x8 af[4], bfr[4];
#pragma unroll
      for (int i = 0; i < 4; ++i) {
        af[i]  = *(const bf16x8*)&Al[(mw * 64 + i * 16 + l15) * 64 + ks * 32 + quad * 8];
        bfr[i] = *(const bf16x8*)&Bl[(nw * 64 + i * 16 + l15) * 64 + ks * 32 + quad * 8];
      }
#pragma unroll
      for (int mi = 0; mi < 4; ++mi)
#pragma unroll
        for (int ni = 0; ni < 4; ++ni)
          acc[mi][ni] = __builtin_amdgcn_mfma_f32_16x16x32_bf16(af[mi], bfr[ni], acc[mi][ni], 0, 0, 0);
    }
  }
}

// ---------------- S = Q K^T, causal lower-triangle tiles, f16 out ----------
// Per batch. Q,K: [4096][1024] bf16 (Q pre-scaled by 1/sqrt(D)). S: [4096][4096] f16.
__global__ __launch_bounds__(256) void qk_gemm(
    const unsigned short* __restrict__ Q,
    const unsigned short* __restrict__ K,
    unsigned short* __restrict__ S)
{
  const int tj = blockIdx.x, ti = blockIdx.y;   // key tile, query tile
  if (tj > ti) return;                          // strictly-upper tiles never read

  __shared__ unsigned short Al[128 * 64];
  __shared__ unsigned short Bl[128 * 64];
  f32x4 acc[4][4] = {};

  mfma_tile128(Q + (size_t)(ti * 128) * DIM, DIM,
               K + (size_t)(tj * 128) * DIM, DIM, DIM, Al, Bl, acc);

  const int tid = threadIdx.x, ln = tid & 63, wv = tid >> 6;
  const int l15 = ln & 15, quad = ln >> 4;
  const int mw = wv >> 1, nw = wv & 1;
  const int m0 = ti * 128, n0 = tj * 128;
#pragma unroll
  for (int mi = 0; mi < 4; ++mi)
#pragma unroll
    for (int ni = 0; ni < 4; ++ni) {
      const int m = m0 + mw * 64 + mi * 16 + quad * 4;
      const int e = n0 + nw * 64 + ni * 16 + l15;
      unsigned short* p = S + (size_t)m * SEQ + e;
#pragma unroll
      for (int r = 0; r < 4; ++r) p[(size_t)r * SEQ] = f2h(acc[mi][ni][r]);
    }
}

// ---------------- row softmax: f16 scores in, normalized bf16 probs out ----
// One block per row. Causal: cols 0..r valid; zero-fill (r, 128*ceil) so the
// PV GEMM can read whole 128-key tiles.
__global__ __launch_bounds__(256) void sm_rows(unsigned short* __restrict__ S)
{
  const int r = blockIdx.x;
  const int len = r + 1;
  const int bound = ((r >> 7) + 1) << 7;   // end of diagonal 128-tile
  const int t = threadIdx.x;
  const int c0 = t * 16;
  unsigned short* row = S + (size_t)r * SEQ;
  __shared__ float red[8];

  u16x8 h0 = *(const u16x8*)(row + c0);
  u16x8 h1 = *(const u16x8*)(row + c0 + 8);
  float v[16];
#pragma unroll
  for (int i = 0; i < 8; ++i) { v[i] = h2f(h0[i]); v[8 + i] = h2f(h1[i]); }

  float mx = -1e30f;
#pragma unroll
  for (int i = 0; i < 16; ++i) {
    if (c0 + i >= len) v[i] = -1e30f;     // mask garbage (may be NaN) first
    mx = fmaxf(mx, v[i]);
  }
#pragma unroll
  for (int off = 1; off < 64; off <<= 1) mx = fmaxf(mx, __shfl_xor(mx, off));
  if ((t & 63) == 0) red[t >> 6] = mx;
  __syncthreads();
  mx = fmaxf(fmaxf(red[0], red[1]), fmaxf(red[2], red[3]));

  float p[16];
  float sm = 0.f;
#pragma unroll
  for (int i = 0; i < 16; ++i) {
    p[i] = (c0 + i < len) ? __expf(v[i] - mx) : 0.f;
    sm += p[i];
  }
#pragma unroll
  for (int off = 1; off < 64; off <<= 1) sm += __shfl_xor(sm, off);
  if ((t & 63) == 0) red[4 + (t >> 6)] = sm;
  __syncthreads();
  const float inv = 1.f / (red[4] + red[5] + red[6] + red[7]);

  if (c0 < bound) {                        // bound % 16 == 0: chunk all-in or all-out
    u16x8 o0, o1;
#pragma unroll
    for (int i = 0; i < 8; ++i) {
      o0[i] = f2bf(p[i] * inv);
      o1[i] = f2bf(p[8 + i] * inv);
    }
    *(u16x8*)(row + c0) = o0;
    *(u16x8*)(row + c0 + 8) = o1;
  }
}

// ---------------- O = P * V via Vt: causal-truncated K loop, f32 out -------
// P: [4096][4096] bf16 row-major. Vt: [1024][4096] bf16 (dim-major). Ob: [4096][1024] f32.
__global__ __launch_bounds__(256) void pv_gemm(
    const unsigned short* __restrict__ P,
    const unsigned short* __restrict__ Vt,
    float* __restrict__ Ob)
{
  const int ti = blockIdx.y;                // query tile
  const int n0 = blockIdx.x * 128;          // output-dim tile
  const int m0 = ti * 128;
  const int kmax = (ti + 1) * 128;          // causal key bound (tile-rounded)

  __shared__ unsigned short Al[128 * 64];
  __shared__ unsigned short Bl[128 * 64];
  f32x4 acc[4][4] = {};

  mfma_tile128(P + (size_t)m0 * SEQ, SEQ,
               Vt + (size_t)n0 * SEQ, SEQ, kmax, Al, Bl, acc);

  const int tid = threadIdx.x, ln = tid & 63, wv = tid >> 6;
  const int l15 = ln & 15, quad = ln >> 4;
  const int mw = wv >> 1, nw = wv & 1;
#pragma unroll
  for (int mi = 0; mi < 4; ++mi)
#pragma unroll
    for (int ni = 0; ni < 4; ++ni) {
      const int m = m0 + mw * 64 + mi * 16 + quad * 4;
      const int e = n0 + nw * 64 + ni * 16 + l15;
      float* p = Ob + (size_t)m * DIM + e;
#pragma unroll
      for (int r = 0; r < 4; ++r) p[(size_t)r * DIM] = acc[mi][ni][r];
    }
}

extern "C" void kernel_launch(void* const* d_in, const int* in_sizes, int n_in,
                              void* d_out, int out_size, void* d_ws, size_t ws_size,
                              hipStream_t stream) {
  const float* x  = (const float*)d_in[0];
  const float* Wq = (const float*)d_in[1];
  const float* Wk = (const float*)d_in[2];
  const float* Wv = (const float*)d_in[3];
  float* out = (float*)d_out;

  // ws layout (134.25 MB), unchanged footprint:
  //   [0,32MB):    xb (bf16 x)        -> later reused as S/P [4096][4096] per batch
  //   [32,38MB):   Wb (bf16 Wq|Wk|Wv)
  //   [38,70MB):   Q bf16   [70,102MB): K bf16   [102,134MB): Vt bf16
  char* wsb = (char*)d_ws;
  unsigned short* xb = (unsigned short*)wsb;
  unsigned short* Wb = (unsigned short*)(wsb + (32u << 20));
  unsigned short* Qb = (unsigned short*)(wsb + (38u << 20));
  unsigned short* Sb = xb;                  // 4096*4096*2B = 32 MB, per-batch scratch

  conv_bf16<<<8192, 256, 0, stream>>>(x,  xb, 2097152, 1.0f);
  conv_bf16<<<512,  256, 0, stream>>>(Wq, Wb,           131072, 0.03125f); // fold 1/sqrt(D)
  conv_bf16<<<512,  256, 0, stream>>>(Wk, Wb + 1048576, 131072, 1.0f);
  conv_bf16<<<512,  256, 0, stream>>>(Wv, Wb + 2097152, 131072, 1.0f);

  qkv_gemm2<<<dim3(8, 128, 3), 256, 0, stream>>>(xb, Wb, Qb);

  const size_t n = (size_t)MTOT * DIM;
  for (int b = 0; b < 4; ++b) {
    const unsigned short* Qp  = Qb + (size_t)b * SEQ * DIM;
    const unsigned short* Kp  = Qb + n + (size_t)b * SEQ * DIM;
    const unsigned short* Vtp = Qb + 2 * n + (size_t)b * DIM * SEQ;
    float* Op = out + (size_t)b * SEQ * DIM;

    qk_gemm<<<dim3(32, 32), 256, 0, stream>>>(Qp, Kp, Sb);
    sm_rows<<<SEQ, 256, 0, stream>>>(Sb);
    pv_gemm<<<dim3(8, 32), 256, 0, stream>>>(Sb, Vtp, Op);
  }
}

// Round 2
// 598.706 us; speedup vs baseline: 1.4321x; 1.4321x over previous
//
#include <hip/hip_runtime.h>
#include <hip/hip_bf16.h>

typedef __attribute__((ext_vector_type(8))) short bf16x8;
typedef __attribute__((ext_vector_type(4))) float f32x4;
typedef __attribute__((ext_vector_type(4))) unsigned short u16x4;
typedef __attribute__((ext_vector_type(8))) unsigned short u16x8;

#define SEQ   4096
#define DIM   1024
#define MTOT  16384
#define NTILE 32            // SEQ/128 query tiles
#define NTRI  528           // NTILE*(NTILE+1)/2 causal tiles
#define TSZ   16384         // elements per 128x128 tile
#define PSIZE ((size_t)NTRI * TSZ)   // packed S elems per batch

static __device__ __forceinline__ unsigned short f2bf(float f) {
  union { float f; unsigned u; } v; v.f = f;
  unsigned r = v.u + 0x7FFFu + ((v.u >> 16) & 1u);
  return (unsigned short)(r >> 16);
}

static __device__ __forceinline__ unsigned short f2h(float f) {
  union { _Float16 h; unsigned short u; } v; v.h = (_Float16)f; return v.u;
}

static __device__ __forceinline__ float h2f(unsigned short u) {
  union { unsigned short u; _Float16 h; } v; v.u = u; return (float)v.h;
}

static __device__ __forceinline__ bf16x8 pack8(f32x4 a, f32x4 b) {
  bf16x8 v;
  v[0]=(short)f2bf(a[0]); v[1]=(short)f2bf(a[1]);
  v[2]=(short)f2bf(a[2]); v[3]=(short)f2bf(a[3]);
  v[4]=(short)f2bf(b[0]); v[5]=(short)f2bf(b[1]);
  v[6]=(short)f2bf(b[2]); v[7]=(short)f2bf(b[3]);
  return v;
}

// row index of lower-triangle tile id (id = ti*(ti+1)/2 + tj)
static __device__ __forceinline__ int tri_row(int id) {
  int ti = (int)((sqrtf(8.f * (float)id + 1.f) - 1.f) * 0.5f);
  while ((ti + 1) * (ti + 2) / 2 <= id) ++ti;
  while (ti * (ti + 1) / 2 > id) --ti;
  return ti;
}

// ---------------- fp32 -> bf16 preconvert ----------------
__global__ __launch_bounds__(256) void conv_bf16(
    const float* __restrict__ src, unsigned short* __restrict__ dst,
    int n8, float scale)
{
  const int i = blockIdx.x * 256 + threadIdx.x;
  if (i < n8) {
    const f32x4* s = (const f32x4*)(src + (size_t)i * 8);
    f32x4 a = s[0], b = s[1];
#pragma unroll
    for (int r = 0; r < 4; ++r) { a[r] *= scale; b[r] *= scale; }
    *(bf16x8*)(dst + (size_t)i * 8) = pack8(a, b);
  }
}

// all three weights in one launch; Wq gets 1/sqrt(D) folded in
__global__ __launch_bounds__(256) void conv_w3(
    const float* __restrict__ Wq, const float* __restrict__ Wk,
    const float* __restrict__ Wv, unsigned short* __restrict__ dst)
{
  const int i = blockIdx.x * 256 + threadIdx.x;   // 0..393215 (x8 elems)
  const int seg = i >> 17;                        // 131072 per weight
  const int loc = i & 131071;
  const float* src = (seg == 0) ? Wq : (seg == 1) ? Wk : Wv;
  const float scale = (seg == 0) ? 0.03125f : 1.0f;
  const f32x4* s = (const f32x4*)(src + (size_t)loc * 8);
  f32x4 a = s[0], b = s[1];
#pragma unroll
  for (int r = 0; r < 4; ++r) { a[r] *= scale; b[r] *= scale; }
  *(bf16x8*)(dst + (size_t)i * 8) = pack8(a, b);
}

// ---------------- shared 128x128-tile GEMM mainloop (m97 structure) ---------
// C[128m x 128n] += A * B^T over k in [0,kmax). Abase/Bbase at tile row 0.
static __device__ __forceinline__ void mfma_tile128(
    const unsigned short* __restrict__ Abase, int lda,
    const unsigned short* __restrict__ Bbase, int ldb,
    int kmax, unsigned short* Al, unsigned short* Bl, f32x4 (&acc)[4][4])
{
  const int tid = threadIdx.x, ln = tid & 63, wv = tid >> 6;
  const int l15 = ln & 15, quad = ln >> 4;
  const int mw = wv >> 1, nw = wv & 1;
  const int lrow = ln >> 3, lcol = (ln & 7) * 8;

  for (int k0 = 0; k0 < kmax; k0 += 64) {
    __syncthreads();   // prior fragment reads done before DMA overwrites LDS
#pragma unroll
    for (int r = 0; r < 4; ++r) {
      const int rr = (wv * 4 + r) * 8 + lrow;
      const unsigned short* ga = Abase + (size_t)rr * lda + k0 + lcol;
      const unsigned short* gb = Bbase + (size_t)rr * ldb + k0 + lcol;
      __builtin_amdgcn_global_load_lds(
          (const __attribute__((address_space(1))) void*)ga,
          (__attribute__((address_space(3))) void*)&Al[(wv * 4 + r) * 512], 16, 0, 0);
      __builtin_amdgcn_global_load_lds(
          (const __attribute__((address_space(1))) void*)gb,
          (__attribute__((address_space(3))) void*)&Bl[(wv * 4 + r) * 512], 16, 0, 0);
    }
    __syncthreads();   // vmcnt(0) drain: DMA complete, LDS valid
#pragma unroll
    for (int ks = 0; ks < 2; ++ks) {
      bf16x8 af[4], bfr[4];
#pragma unroll
      for (int i = 0; i < 4; ++i) {
        af[i]  = *(const bf16x8*)&Al[(mw * 64 + i * 16 + l15) * 64 + ks * 32 + quad * 8];
        bfr[i] = *(const bf16x8*)&Bl[(nw * 64 + i * 16 + l15) * 64 + ks * 32 + quad * 8];
      }
#pragma unroll
      for (int mi = 0; mi < 4; ++mi)
#pragma unroll
        for (int ni = 0; ni < 4; ++ni)
          acc[mi][ni] = __builtin_amdgcn_mfma_f32_16x16x32_bf16(af[mi], bfr[ni], acc[mi][ni], 0, 0, 0);
    }
  }
}

// ---------------- QKV GEMM: XCD-panel-swizzled 1D grid ----------------------
// bid -> xcd=bid&7; panel pid=xcd*48+(i>>3), x=i&7. All 8 n-blocks of a panel
// plus consecutive m-panels land on ONE XCD -> A-panel (256KB) + Wz (2MB) L2-hot.
__global__ __launch_bounds__(256) void qkv_gemm2(
    const unsigned short* __restrict__ xb,
    const unsigned short* __restrict__ Wb,    // Wq|Wk|Wv bf16
    unsigned short* __restrict__ outQ)        // Q | K | Vt contiguous
{
  const int bid = blockIdx.x;               // 3072
  const int xcd = bid & 7;
  const int i = bid >> 3;                   // 0..383
  const int pid = xcd * 48 + (i >> 3);      // panel 0..383 (z,y)
  const int x = i & 7;
  const int z = pid >> 7;
  const int y = pid & 127;

  const unsigned short* __restrict__ Wz = Wb + (size_t)z * (DIM * DIM);
  unsigned short* __restrict__ outb = outQ + (size_t)z * ((size_t)MTOT * DIM);
  const int n0 = x * 128;
  const int m0 = y * 128;

  __shared__ unsigned short Al[128 * 64];
  __shared__ unsigned short Bl[128 * 64];
  f32x4 acc[4][4] = {};

  mfma_tile128(xb + (size_t)m0 * DIM, DIM, Wz + (size_t)n0 * DIM, DIM, DIM,
               Al, Bl, acc);

  const int tid = threadIdx.x, ln = tid & 63, wv = tid >> 6;
  const int l15 = ln & 15, quad = ln >> 4;
  const int mw = wv >> 1, nw = wv & 1;

  if (z < 2) {
#pragma unroll
    for (int mi = 0; mi < 4; ++mi)
#pragma unroll
      for (int ni = 0; ni < 4; ++ni) {
        const int m = m0 + mw * 64 + mi * 16 + quad * 4;
        const int e = n0 + nw * 64 + ni * 16 + l15;
        unsigned short* p = outb + (size_t)m * DIM + e;
#pragma unroll
        for (int r = 0; r < 4; ++r) p[(size_t)r * DIM] = f2bf(acc[mi][ni][r]);
      }
  } else {
#pragma unroll
    for (int mi = 0; mi < 4; ++mi)
#pragma unroll
      for (int ni = 0; ni < 4; ++ni) {
        const int m = m0 + mw * 64 + mi * 16 + quad * 4;   // s index (4 consec)
        const int e = n0 + nw * 64 + ni * 16 + l15;
        const int bb = m >> 12, ss = m & 4095;
        u16x4 v4;
#pragma unroll
        for (int r = 0; r < 4; ++r) v4[r] = f2bf(acc[mi][ni][r]);
        *(u16x4*)(outb + ((size_t)bb * DIM + e) * SEQ + ss) = v4;
      }
  }
}

// ---------------- S = Q K^T, causal tiles only, packed f16 out --------------
// 2 batches per launch (1056 blocks). Packed layout per batch: tile row ti is
// a [128][(ti+1)*128] row-major block at elem offset tri(ti)*TSZ.
// XCD-chunked: xcd 0-3 -> batch 0, 4-7 -> batch 1; consecutive tri-ids share
// a Q panel.
__global__ __launch_bounds__(256) void qk_gemm_p(
    const unsigned short* __restrict__ Q,
    const unsigned short* __restrict__ K,
    unsigned short* __restrict__ Sp)
{
  const int bid = blockIdx.x;                 // 1056
  const int item = (bid & 7) * 132 + (bid >> 3);
  const int bsel = item >= NTRI;
  const int id = item - (bsel ? NTRI : 0);
  const int ti = tri_row(id);
  const int tj = id - ti * (ti + 1) / 2;

  const unsigned short* Qb = Q + (size_t)bsel * SEQ * DIM;
  const unsigned short* Kb = K + (size_t)bsel * SEQ * DIM;
  unsigned short* Sb = Sp + (size_t)bsel * PSIZE;

  __shared__ unsigned short Al[128 * 64];
  __shared__ unsigned short Bl[128 * 64];
  f32x4 acc[4][4] = {};

  mfma_tile128(Qb + (size_t)(ti * 128) * DIM, DIM,
               Kb + (size_t)(tj * 128) * DIM, DIM, DIM, Al, Bl, acc);

  const int tid = threadIdx.x, ln = tid & 63, wv = tid >> 6;
  const int l15 = ln & 15, quad = ln >> 4;
  const int mw = wv >> 1, nw = wv & 1;
  const int Lt = (ti + 1) << 7;
  unsigned short* base = Sb + (size_t)(ti * (ti + 1) / 2) * TSZ;
#pragma unroll
  for (int mi = 0; mi < 4; ++mi)
#pragma unroll
    for (int ni = 0; ni < 4; ++ni) {
      const int mloc = mw * 64 + mi * 16 + quad * 4;       // row within tile
      const int col  = tj * 128 + nw * 64 + ni * 16 + l15; // global key col
      unsigned short* p = base + (size_t)mloc * Lt + col;
#pragma unroll
      for (int r = 0; r < 4; ++r) p[(size_t)r * Lt] = f2h(acc[mi][ni][r]);
    }
}

// ---------------- row softmax on packed S: f16 in, normalized bf16 out ------
// 8192 blocks = 2 batches x 4096 rows. Row r has Lt=(ti+1)*128 packed cols;
// valid cols 0..r, rest zero-filled so pv reads whole tiles.
__global__ __launch_bounds__(256) void sm_rows_p(unsigned short* __restrict__ Sp)
{
  const int bid = blockIdx.x;
  const int bsel = bid >> 12;
  const int r = bid & 4095;
  const int ti = r >> 7, ri = r & 127;
  const int Lt = (ti + 1) << 7;
  const int len = r + 1;
  unsigned short* row = Sp + (size_t)bsel * PSIZE +
                        (size_t)(ti * (ti + 1) / 2) * TSZ + (size_t)ri * Lt;
  const int t = threadIdx.x;
  __shared__ float red[8];

  float v[16];
#pragma unroll
  for (int it = 0; it < 2; ++it) {
    const int c = t * 8 + it * 2048;
    if (c < Lt) {
      u16x8 h = *(const u16x8*)(row + c);
#pragma unroll
      for (int i = 0; i < 8; ++i)
        v[it * 8 + i] = (c + i < len) ? h2f(h[i]) : -1e30f;
    } else {
#pragma unroll
      for (int i = 0; i < 8; ++i) v[it * 8 + i] = -1e30f;
    }
  }

  float mx = v[0];
#pragma unroll
  for (int i = 1; i < 16; ++i) mx = fmaxf(mx, v[i]);
#pragma unroll
  for (int off = 1; off < 64; off <<= 1) mx = fmaxf(mx, __shfl_xor(mx, off));
  if ((t & 63) == 0) red[t >> 6] = mx;
  __syncthreads();
  mx = fmaxf(fmaxf(red[0], red[1]), fmaxf(red[2], red[3]));

  float p[16];
  float sm = 0.f;
#pragma unroll
  for (int it = 0; it < 2; ++it) {
    const int c = t * 8 + it * 2048;
#pragma unroll
    for (int i = 0; i < 8; ++i) {
      const int k = it * 8 + i;
      p[k] = (c + i < len) ? __expf(v[k] - mx) : 0.f;
      sm += p[k];
    }
  }
#pragma unroll
  for (int off = 1; off < 64; off <<= 1) sm += __shfl_xor(sm, off);
  if ((t & 63) == 0) red[4 + (t >> 6)] = sm;
  __syncthreads();
  const float inv = 1.f / (red[4] + red[5] + red[6] + red[7]);

#pragma unroll
  for (int it = 0; it < 2; ++it) {
    const int c = t * 8 + it * 2048;
    if (c < Lt) {
      u16x8 o;
#pragma unroll
      for (int i = 0; i < 8; ++i) o[i] = f2bf(p[it * 8 + i] * inv);
      *(u16x8*)(row + c) = o;
    }
  }
}

// ---------------- O = P * V: pair-balanced causal GEMM ----------------------
// 256 blocks = 2 batches x 8 dslices x 16 pairs; each block does query tiles
// ti=pr and 31-pr -> uniform 33 k-tiles. XCD-chunked: each XCD owns 2 dslices
// of one batch -> its 2 Vt panels (2MB) stay L2-resident.
__global__ __launch_bounds__(256) void pv_gemm_p(
    const unsigned short* __restrict__ Sp,
    const unsigned short* __restrict__ Vt,
    float* __restrict__ Ob)
{
  const int bid = blockIdx.x;                 // 256
  const int item = (bid & 7) * 32 + (bid >> 3);
  const int bsel = item >> 7;
  const int rem = item & 127;
  const int x  = rem >> 4;                    // output-dim slice
  const int pr = rem & 15;                    // pair id

  const unsigned short* Sb = Sp + (size_t)bsel * PSIZE;
  const unsigned short* Vb = Vt + (size_t)bsel * ((size_t)DIM * SEQ) +
                             (size_t)(x * 128) * SEQ;
  float* Outb = Ob + (size_t)bsel * ((size_t)SEQ * DIM);

  __shared__ unsigned short Al[128 * 64];
  __shared__ unsigned short Bl[128 * 64];

  const int tid = threadIdx.x, ln = tid & 63, wv = tid >> 6;
  const int l15 = ln & 15, quad = ln >> 4;
  const int mw = wv >> 1, nw = wv & 1;

#pragma unroll 1
  for (int half = 0; half < 2; ++half) {
    const int ti = half ? (31 - pr) : pr;
    const int Lt = (ti + 1) << 7;
    f32x4 acc[4][4] = {};

    mfma_tile128(Sb + (size_t)(ti * (ti + 1) / 2) * TSZ, Lt,
                 Vb, SEQ, Lt, Al, Bl, acc);

#pragma unroll
    for (int mi = 0; mi < 4; ++mi)
#pragma unroll
      for (int ni = 0; ni < 4; ++ni) {
        const int m = ti * 128 + mw * 64 + mi * 16 + quad * 4;
        const int e = x * 128 + nw * 64 + ni * 16 + l15;
        float* p = Outb + (size_t)m * DIM + e;
#pragma unroll
        for (int r = 0; r < 4; ++r) p[(size_t)r * DIM] = acc[mi][ni][r];
      }
  }
}

extern "C" void kernel_launch(void* const* d_in, const int* in_sizes, int n_in,
                              void* d_out, int out_size, void* d_ws, size_t ws_size,
                              hipStream_t stream) {
  const float* x  = (const float*)d_in[0];
  const float* Wq = (const float*)d_in[1];
  const float* Wk = (const float*)d_in[2];
  const float* Wv = (const float*)d_in[3];
  float* out = (float*)d_out;

  // ws layout (134.25 MB), unchanged footprint:
  //   [0,38MB):    xb (bf16 x, 32MB) + Wb (bf16 weights, 6MB)
  //                -> after qkv: packed-causal S for 2 batches (2 x 16.5MB)
  //   [38,70MB):   Q bf16   [70,102MB): K bf16   [102,134MB): Vt bf16
  char* wsb = (char*)d_ws;
  unsigned short* xb = (unsigned short*)wsb;
  unsigned short* Wb = (unsigned short*)(wsb + (32u << 20));
  unsigned short* Qb = (unsigned short*)(wsb + (38u << 20));
  unsigned short* Sp = xb;   // 2 x PSIZE x 2B = 33 MB <= 38 MB

  conv_bf16<<<8192, 256, 0, stream>>>(x, xb, 2097152, 1.0f);
  conv_w3<<<1536, 256, 0, stream>>>(Wq, Wk, Wv, Wb);

  qkv_gemm2<<<3072, 256, 0, stream>>>(xb, Wb, Qb);

  const size_t n = (size_t)MTOT * DIM;
  for (int p = 0; p < 2; ++p) {
    const unsigned short* Qp  = Qb + (size_t)p * 2 * SEQ * DIM;
    const unsigned short* Kp  = Qb + n + (size_t)p * 2 * SEQ * DIM;
    const unsigned short* Vtp = Qb + 2 * n + (size_t)p * 2 * DIM * SEQ;
    float* Op = out + (size_t)p * 2 * SEQ * DIM;

    qk_gemm_p<<<1056, 256, 0, stream>>>(Qp, Kp, Sp);
    sm_rows_p<<<8192, 256, 0, stream>>>(Sp);
    pv_gemm_p<<<256, 256, 0, stream>>>(Sp, Vtp, Op);
  }
}

// Round 3
// 584.613 us; speedup vs baseline: 1.4666x; 1.0241x over previous
//
#include <hip/hip_runtime.h>
#include <hip/hip_bf16.h>

typedef __attribute__((ext_vector_type(8))) short bf16x8;
typedef __attribute__((ext_vector_type(4))) float f32x4;
typedef __attribute__((ext_vector_type(4))) unsigned short u16x4;
typedef __attribute__((ext_vector_type(8))) unsigned short u16x8;

#define SEQ   4096
#define DIM   1024
#define MTOT  16384
#define NT256 16            // SEQ/256 query tiles (256-granular)
#define NTRI2 136           // NT256*(NT256+1)/2 causal 256-tiles
#define TSZ2  65536         // elements per 256x256 tile
#define PSIZE2 ((size_t)NTRI2 * TSZ2)   // packed S elems per batch (8.9M)

static __device__ __forceinline__ unsigned short f2bf(float f) {
  union { float f; unsigned u; } v; v.f = f;
  unsigned r = v.u + 0x7FFFu + ((v.u >> 16) & 1u);
  return (unsigned short)(r >> 16);
}

static __device__ __forceinline__ unsigned short f2h(float f) {
  union { _Float16 h; unsigned short u; } v; v.h = (_Float16)f; return v.u;
}

static __device__ __forceinline__ float h2f(unsigned short u) {
  union { unsigned short u; _Float16 h; } v; v.u = u; return (float)v.h;
}

static __device__ __forceinline__ bf16x8 pack8(f32x4 a, f32x4 b) {
  bf16x8 v;
  v[0]=(short)f2bf(a[0]); v[1]=(short)f2bf(a[1]);
  v[2]=(short)f2bf(a[2]); v[3]=(short)f2bf(a[3]);
  v[4]=(short)f2bf(b[0]); v[5]=(short)f2bf(b[1]);
  v[6]=(short)f2bf(b[2]); v[7]=(short)f2bf(b[3]);
  return v;
}

// row index of lower-triangle tile id (id = ti*(ti+1)/2 + tj)
static __device__ __forceinline__ int tri_row(int id) {
  int ti = (int)((sqrtf(8.f * (float)id + 1.f) - 1.f) * 0.5f);
  while ((ti + 1) * (ti + 2) / 2 <= id) ++ti;
  while (ti * (ti + 1) / 2 > id) --ti;
  return ti;
}

// ---------------- fp32 -> bf16 preconvert ----------------
__global__ __launch_bounds__(256) void conv_bf16(
    const float* __restrict__ src, unsigned short* __restrict__ dst,
    int n8, float scale)
{
  const int i = blockIdx.x * 256 + threadIdx.x;
  if (i < n8) {
    const f32x4* s = (const f32x4*)(src + (size_t)i * 8);
    f32x4 a = s[0], b = s[1];
#pragma unroll
    for (int r = 0; r < 4; ++r) { a[r] *= scale; b[r] *= scale; }
    *(bf16x8*)(dst + (size_t)i * 8) = pack8(a, b);
  }
}

// all three weights in one launch; Wq gets 1/sqrt(D) folded in
__global__ __launch_bounds__(256) void conv_w3(
    const float* __restrict__ Wq, const float* __restrict__ Wk,
    const float* __restrict__ Wv, unsigned short* __restrict__ dst)
{
  const int i = blockIdx.x * 256 + threadIdx.x;
  const int seg = i >> 17;
  const int loc = i & 131071;
  const float* src = (seg == 0) ? Wq : (seg == 1) ? Wk : Wv;
  const float scale = (seg == 0) ? 0.03125f : 1.0f;
  const f32x4* s = (const f32x4*)(src + (size_t)loc * 8);
  f32x4 a = s[0], b = s[1];
#pragma unroll
  for (int r = 0; r < 4; ++r) { a[r] *= scale; b[r] *= scale; }
  *(bf16x8*)(dst + (size_t)i * 8) = pack8(a, b);
}

// ============================================================================
// 256x256-tile GEMM core pieces (8 waves, BK=64, counted-vmcnt double buffer).
// LDS: Au[2][256][64], Bu[2][256][64] bf16 = 128 KiB.
// Swizzle (both-sides involution, rule 21): LDS(row, c) = G(row, c ^ sw(row)),
// sw(row) = ((row>>2)&3)<<4 elements. Staging pre-swizzles the GLOBAL column;
// ds_read applies the same XOR. Breaks the 16-lane same-bank column read.
// Pipeline invariant: buf p for tile v is (a) only read after vmcnt(<=8) +
// barrier prove all 8 of its loads landed in every wave, (b) only re-staged
// (tile v+2) after the barrier that follows the last read of tile v.
// ============================================================================

// stage one 64-K tile (8 global_load_lds per thread: 4 rounds x {A,B})
static __device__ __forceinline__ void stage256(
    const unsigned short* __restrict__ Ab,   // tile row 0 of A, + k0
    const unsigned short* __restrict__ Bb,   // tile row 0 of B, + k0
    int lda, int ldb,
    unsigned short* Au, unsigned short* Bu, int tid)
{
  const int w = tid >> 6;
  const int srow = tid >> 3;            // 0..63 within round
  const int scol = (tid & 7) * 8;       // element col
#pragma unroll
  for (int L = 0; L < 4; ++L) {
    const int row = L * 64 + srow;
    const int sw = ((row >> 2) & 3) << 4;
    const unsigned short* ga = Ab + (size_t)row * lda + (scol ^ sw);
    const unsigned short* gb = Bb + (size_t)row * ldb + (scol ^ sw);
    __builtin_amdgcn_global_load_lds(
        (const __attribute__((address_space(1))) void*)ga,
        (__attribute__((address_space(3))) void*)&Au[(L * 64 + w * 8) * 64], 16, 0, 0);
    __builtin_amdgcn_global_load_lds(
        (const __attribute__((address_space(1))) void*)gb,
        (__attribute__((address_space(3))) void*)&Bu[(L * 64 + w * 8) * 64], 16, 0, 0);
  }
}

// compute one 64-K tile from buf: 64 MFMA/wave
static __device__ __forceinline__ void compute256(
    const unsigned short* Au, const unsigned short* Bu,
    int wr, int wc, int l15, int quad, f32x4 (&acc)[8][4])
{
  const int csw = (l15 >> 2) << 4;      // row bits2,3 == l15 bits2,3
  bf16x8 bfr[4][2];
#pragma unroll
  for (int fn = 0; fn < 4; ++fn)
#pragma unroll
    for (int ks = 0; ks < 2; ++ks) {
      const int row = wc * 64 + fn * 16 + l15;
      bfr[fn][ks] = *(const bf16x8*)&Bu[row * 64 + ((ks * 32 + quad * 8) ^ csw)];
    }
  __builtin_amdgcn_s_setprio(1);
#pragma unroll
  for (int h = 0; h < 2; ++h) {
    bf16x8 af[4][2];
#pragma unroll
    for (int f = 0; f < 4; ++f)
#pragma unroll
      for (int ks = 0; ks < 2; ++ks) {
        const int row = wr * 128 + h * 64 + f * 16 + l15;
        af[f][ks] = *(const bf16x8*)&Au[row * 64 + ((ks * 32 + quad * 8) ^ csw)];
      }
#pragma unroll
    for (int ks = 0; ks < 2; ++ks)
#pragma unroll
      for (int f = 0; f < 4; ++f)
#pragma unroll
        for (int fn = 0; fn < 4; ++fn)
          acc[h * 4 + f][fn] = __builtin_amdgcn_mfma_f32_16x16x32_bf16(
              af[f][ks], bfr[fn][ks], acc[h * 4 + f][fn], 0, 0, 0);
  }
  __builtin_amdgcn_s_setprio(0);
}

static __device__ __forceinline__ void head_sync(bool more) {
  if (more) asm volatile("s_waitcnt vmcnt(8)" ::: "memory");
  else      asm volatile("s_waitcnt vmcnt(0)" ::: "memory");
  __builtin_amdgcn_s_barrier();
  asm volatile("" ::: "memory");
}

static __device__ __forceinline__ void tail_sync() {
  asm volatile("" ::: "memory");
  __builtin_amdgcn_s_barrier();
  asm volatile("" ::: "memory");
}

// ---------------- QKV GEMM, z-fused: 256 blocks x 512 thr, 48 K-tiles -------
// Block owns one (m-tile, n-tile); loops z=0,1,2 through one continuous
// software pipeline (A restaged per z from L2; B from Wz).
__global__ __launch_bounds__(512, 2) void qkv_gemm3(
    const unsigned short* __restrict__ xb,
    const unsigned short* __restrict__ Wb,
    unsigned short* __restrict__ outQ)
{
  __shared__ unsigned short Au[2][256 * 64];
  __shared__ unsigned short Bu[2][256 * 64];

  const int bid = blockIdx.x;               // 256
  const int xcd = bid & 7, i = bid >> 3;
  const int mt = xcd * 8 + (i >> 2);        // 0..63  (A-panel locality per XCD)
  const int nt = i & 3;                     // 0..3
  const int m0 = mt * 256, n0 = nt * 256;

  const int tid = threadIdx.x;
  const int w = tid >> 6, ln = tid & 63;
  const int l15 = ln & 15, quad = ln >> 4;
  const int wr = w >> 2, wc = w & 3;

  const unsigned short* Ab0 = xb + (size_t)m0 * DIM;

  f32x4 acc[8][4] = {};

  auto stage_v = [&](int v, int p) {
    const int z = v >> 4, k0 = (v & 15) * 64;
    const unsigned short* Bz = Wb + (size_t)z * (DIM * DIM) + (size_t)n0 * DIM;
    stage256(Ab0 + k0, Bz + k0, DIM, DIM, Au[p], Bu[p], tid);
  };

  stage_v(0, 0);
  stage_v(1, 1);

#pragma unroll 1
  for (int v = 0; v < 48; ++v) {
    const int p = v & 1;
    head_sync(v + 1 < 48);
    compute256(Au[p], Bu[p], wr, wc, l15, quad, acc);
    tail_sync();
    if (v + 2 < 48) stage_v(v + 2, p);

    if ((v & 15) == 15) {
      const int z = v >> 4;
      unsigned short* outb = outQ + (size_t)z * ((size_t)MTOT * DIM);
      if (z < 2) {
#pragma unroll
        for (int fm = 0; fm < 8; ++fm)
#pragma unroll
          for (int fn = 0; fn < 4; ++fn) {
            const int m = m0 + wr * 128 + fm * 16 + quad * 4;
            const int e = n0 + wc * 64 + fn * 16 + l15;
            unsigned short* pp = outb + (size_t)m * DIM + e;
#pragma unroll
            for (int r = 0; r < 4; ++r) pp[(size_t)r * DIM] = f2bf(acc[fm][fn][r]);
          }
      } else {
#pragma unroll
        for (int fm = 0; fm < 8; ++fm)
#pragma unroll
          for (int fn = 0; fn < 4; ++fn) {
            const int m = m0 + wr * 128 + fm * 16 + quad * 4;   // s index
            const int e = n0 + wc * 64 + fn * 16 + l15;         // dim index
            const int bb = m >> 12, ss = m & 4095;
            u16x4 v4;
#pragma unroll
            for (int r = 0; r < 4; ++r) v4[r] = f2bf(acc[fm][fn][r]);
            *(u16x4*)(outb + ((size_t)bb * DIM + e) * SEQ + ss) = v4;
          }
      }
#pragma unroll
      for (int fm = 0; fm < 8; ++fm)
#pragma unroll
        for (int fn = 0; fn < 4; ++fn) acc[fm][fn] = (f32x4){0.f, 0.f, 0.f, 0.f};
    }
  }
}

// ---------------- S = Q K^T, 256-granular causal tiles, packed f16 ----------
// 272 blocks = 2 batches x 136 tri tiles. Packed: tile row TI is a
// [256][(TI+1)*256] row-major block at elem offset TI*(TI+1)/2 * TSZ2.
__global__ __launch_bounds__(512, 2) void qk_gemm3(
    const unsigned short* __restrict__ Q,
    const unsigned short* __restrict__ K,
    unsigned short* __restrict__ Sp)
{
  __shared__ unsigned short Au[2][256 * 64];
  __shared__ unsigned short Bu[2][256 * 64];

  const int bid = blockIdx.x;                       // 272 = 8 x 34
  const int item = (bid & 7) * 34 + (bid >> 3);
  const int bsel = item >= NTRI2;
  const int id = item - (bsel ? NTRI2 : 0);
  const int TI = tri_row(id);
  const int TJ = id - TI * (TI + 1) / 2;

  const unsigned short* Ab0 = Q + (size_t)bsel * SEQ * DIM + (size_t)(TI * 256) * DIM;
  const unsigned short* Bb0 = K + (size_t)bsel * SEQ * DIM + (size_t)(TJ * 256) * DIM;

  const int tid = threadIdx.x;
  const int w = tid >> 6, ln = tid & 63;
  const int l15 = ln & 15, quad = ln >> 4;
  const int wr = w >> 2, wc = w & 3;

  f32x4 acc[8][4] = {};

  stage256(Ab0, Bb0, DIM, DIM, Au[0], Bu[0], tid);
  stage256(Ab0 + 64, Bb0 + 64, DIM, DIM, Au[1], Bu[1], tid);

#pragma unroll 1
  for (int v = 0; v < 16; ++v) {
    const int p = v & 1;
    head_sync(v + 1 < 16);
    compute256(Au[p], Bu[p], wr, wc, l15, quad, acc);
    tail_sync();
    if (v + 2 < 16) stage256(Ab0 + (v + 2) * 64, Bb0 + (v + 2) * 64, DIM, DIM,
                             Au[p], Bu[p], tid);
  }

  const int Lt = (TI + 1) << 8;
  unsigned short* base = Sp + (size_t)bsel * PSIZE2 + (size_t)(TI * (TI + 1) / 2) * TSZ2;
#pragma unroll
  for (int fm = 0; fm < 8; ++fm)
#pragma unroll
    for (int fn = 0; fn < 4; ++fn) {
      const int mloc = wr * 128 + fm * 16 + quad * 4;
      const int col  = TJ * 256 + wc * 64 + fn * 16 + l15;
      unsigned short* pp = base + (size_t)mloc * Lt + col;
#pragma unroll
      for (int r = 0; r < 4; ++r) pp[(size_t)r * Lt] = f2h(acc[fm][fn][r]);
    }
}

// ---------------- row softmax on 256-packed S: f16 in, bf16 out -------------
__global__ __launch_bounds__(256) void sm_rows_p(unsigned short* __restrict__ Sp)
{
  const int bid = blockIdx.x;
  const int bsel = bid >> 12;
  const int r = bid & 4095;
  const int TI = r >> 8, ri = r & 255;
  const int Lt = (TI + 1) << 8;
  const int len = r + 1;
  unsigned short* row = Sp + (size_t)bsel * PSIZE2 +
                        (size_t)(TI * (TI + 1) / 2) * TSZ2 + (size_t)ri * Lt;
  const int t = threadIdx.x;
  __shared__ float red[8];

  float v[16];
#pragma unroll
  for (int it = 0; it < 2; ++it) {
    const int c = t * 8 + it * 2048;
    if (c < Lt) {
      u16x8 h = *(const u16x8*)(row + c);
#pragma unroll
      for (int i = 0; i < 8; ++i)
        v[it * 8 + i] = (c + i < len) ? h2f(h[i]) : -1e30f;
    } else {
#pragma unroll
      for (int i = 0; i < 8; ++i) v[it * 8 + i] = -1e30f;
    }
  }

  float mx = v[0];
#pragma unroll
  for (int i = 1; i < 16; ++i) mx = fmaxf(mx, v[i]);
#pragma unroll
  for (int off = 1; off < 64; off <<= 1) mx = fmaxf(mx, __shfl_xor(mx, off));
  if ((t & 63) == 0) red[t >> 6] = mx;
  __syncthreads();
  mx = fmaxf(fmaxf(red[0], red[1]), fmaxf(red[2], red[3]));

  float p[16];
  float sm = 0.f;
#pragma unroll
  for (int it = 0; it < 2; ++it) {
    const int c = t * 8 + it * 2048;
#pragma unroll
    for (int i = 0; i < 8; ++i) {
      const int k = it * 8 + i;
      p[k] = (c + i < len) ? __expf(v[k] - mx) : 0.f;
      sm += p[k];
    }
  }
#pragma unroll
  for (int off = 1; off < 64; off <<= 1) sm += __shfl_xor(sm, off);
  if ((t & 63) == 0) red[4 + (t >> 6)] = sm;
  __syncthreads();
  const float inv = 1.f / (red[4] + red[5] + red[6] + red[7]);

#pragma unroll
  for (int it = 0; it < 2; ++it) {
    const int c = t * 8 + it * 2048;
    if (c < Lt) {
      u16x8 o;
#pragma unroll
      for (int i = 0; i < 8; ++i) o[i] = f2bf(p[it * 8 + i] * inv);
      *(u16x8*)(row + c) = o;
    }
  }
}

// ---------------- 128x128-tile GEMM mainloop (m97 structure, for PV) --------
static __device__ __forceinline__ void mfma_tile128(
    const unsigned short* __restrict__ Abase, int lda,
    const unsigned short* __restrict__ Bbase, int ldb,
    int kmax, unsigned short* Al, unsigned short* Bl, f32x4 (&acc)[4][4])
{
  const int tid = threadIdx.x, ln = tid & 63, wv = tid >> 6;
  const int l15 = ln & 15, quad = ln >> 4;
  const int mw = wv >> 1, nw = wv & 1;
  const int lrow = ln >> 3, lcol = (ln & 7) * 8;

  for (int k0 = 0; k0 < kmax; k0 += 64) {
    __syncthreads();
#pragma unroll
    for (int r = 0; r < 4; ++r) {
      const int rr = (wv * 4 + r) * 8 + lrow;
      const unsigned short* ga = Abase + (size_t)rr * lda + k0 + lcol;
      const unsigned short* gb = Bbase + (size_t)rr * ldb + k0 + lcol;
      __builtin_amdgcn_global_load_lds(
          (const __attribute__((address_space(1))) void*)ga,
          (__attribute__((address_space(3))) void*)&Al[(wv * 4 + r) * 512], 16, 0, 0);
      __builtin_amdgcn_global_load_lds(
          (const __attribute__((address_space(1))) void*)gb,
          (__attribute__((address_space(3))) void*)&Bl[(wv * 4 + r) * 512], 16, 0, 0);
    }
    __syncthreads();
#pragma unroll
    for (int ks = 0; ks < 2; ++ks) {
      bf16x8 af[4], bfr[4];
#pragma unroll
      for (int i = 0; i < 4; ++i) {
        af[i]  = *(const bf16x8*)&Al[(mw * 64 + i * 16 + l15) * 64 + ks * 32 + quad * 8];
        bfr[i] = *(const bf16x8*)&Bl[(nw * 64 + i * 16 + l15) * 64 + ks * 32 + quad * 8];
      }
#pragma unroll
      for (int mi = 0; mi < 4; ++mi)
#pragma unroll
        for (int ni = 0; ni < 4; ++ni)
          acc[mi][ni] = __builtin_amdgcn_mfma_f32_16x16x32_bf16(af[mi], bfr[ni], acc[mi][ni], 0, 0, 0);
    }
  }
}

// ---------------- O = P * V on 256-packed S ---------------------------------
// 512 blocks = 2b x 8d x 32 ti128. Dispatch-order balance: blocks j and j+256
// get complementary ti (q and 31-q) so round-robin dispatch pairs them on one
// CU. d = bid&7 keeps each XCD on one Vt panel per batch.
__global__ __launch_bounds__(256) void pv_gemm_p(
    const unsigned short* __restrict__ Sp,
    const unsigned short* __restrict__ Vt,
    float* __restrict__ Ob)
{
  const int bid = blockIdx.x;                 // 512
  const int d = bid & 7;
  const int rr_ = bid >> 3;                   // 0..63
  const int b = rr_ & 1;
  const int q = rr_ >> 1;                     // 0..31
  const int ti = (q & 16) ? (31 - (q & 15)) : q;

  const int TI = ti >> 1;
  const int Lt = (TI + 1) << 8;

  const unsigned short* Sb = Sp + (size_t)b * PSIZE2 +
                             (size_t)(TI * (TI + 1) / 2) * TSZ2 +
                             (size_t)(ti & 1) * 128 * Lt;
  const unsigned short* Vb = Vt + (size_t)b * ((size_t)DIM * SEQ) +
                             (size_t)(d * 128) * SEQ;
  float* Outb = Ob + (size_t)b * ((size_t)SEQ * DIM);

  __shared__ unsigned short Al[128 * 64];
  __shared__ unsigned short Bl[128 * 64];
  f32x4 acc[4][4] = {};

  mfma_tile128(Sb, Lt, Vb, SEQ, Lt, Al, Bl, acc);

  const int tid = threadIdx.x, ln = tid & 63, wv = tid >> 6;
  const int l15 = ln & 15, quad = ln >> 4;
  const int mw = wv >> 1, nw = wv & 1;
#pragma unroll
  for (int mi = 0; mi < 4; ++mi)
#pragma unroll
    for (int ni = 0; ni < 4; ++ni) {
      const int m = ti * 128 + mw * 64 + mi * 16 + quad * 4;
      const int e = d * 128 + nw * 64 + ni * 16 + l15;
      float* pp = Outb + (size_t)m * DIM + e;
#pragma unroll
      for (int r = 0; r < 4; ++r) pp[(size_t)r * DIM] = acc[mi][ni][r];
    }
}

extern "C" void kernel_launch(void* const* d_in, const int* in_sizes, int n_in,
                              void* d_out, int out_size, void* d_ws, size_t ws_size,
                              hipStream_t stream) {
  const float* x  = (const float*)d_in[0];
  const float* Wq = (const float*)d_in[1];
  const float* Wk = (const float*)d_in[2];
  const float* Wv = (const float*)d_in[3];
  float* out = (float*)d_out;

  // ws layout (134.25 MB):
  //   [0,38MB):    xb (bf16 x, 32MB) + Wb (bf16 weights, 6MB)
  //                -> after qkv: 256-packed causal S, 2 batches (2 x 17.8MB;
  //                   spills 3.7MB into dead Wb region)
  //   [38,70MB):   Q bf16   [70,102MB): K bf16   [102,134MB): Vt bf16
  char* wsb = (char*)d_ws;
  unsigned short* xb = (unsigned short*)wsb;
  unsigned short* Wb = (unsigned short*)(wsb + (32u << 20));
  unsigned short* Qb = (unsigned short*)(wsb + (38u << 20));
  unsigned short* Sp = xb;

  conv_bf16<<<8192, 256, 0, stream>>>(x, xb, 2097152, 1.0f);
  conv_w3<<<1536, 256, 0, stream>>>(Wq, Wk, Wv, Wb);

  qkv_gemm3<<<256, 512, 0, stream>>>(xb, Wb, Qb);

  const size_t n = (size_t)MTOT * DIM;
  for (int p = 0; p < 2; ++p) {
    const unsigned short* Qp  = Qb + (size_t)p * 2 * SEQ * DIM;
    const unsigned short* Kp  = Qb + n + (size_t)p * 2 * SEQ * DIM;
    const unsigned short* Vtp = Qb + 2 * n + (size_t)p * 2 * DIM * SEQ;
    float* Op = out + (size_t)p * 2 * SEQ * DIM;

    qk_gemm3<<<272, 512, 0, stream>>>(Qp, Kp, Sp);
    sm_rows_p<<<8192, 256, 0, stream>>>(Sp);
    pv_gemm_p<<<512, 256, 0, stream>>>(Sp, Vtp, Op);
  }
}

// Round 4
// 530.776 us; speedup vs baseline: 1.6153x; 1.1014x over previous
//
#include <hip/hip_runtime.h>
#include <hip/hip_bf16.h>

typedef __attribute__((ext_vector_type(8))) short bf16x8;
typedef __attribute__((ext_vector_type(4))) float f32x4;
typedef __attribute__((ext_vector_type(4))) unsigned short u16x4;
typedef __attribute__((ext_vector_type(8))) unsigned short u16x8;

#define SEQ   4096
#define DIM   1024
#define MTOT  16384
#define NTILE 32            // SEQ/128 query tiles (128-granular packing)
#define NTRI  528           // NTILE*(NTILE+1)/2 causal tiles
#define TSZ   16384         // elements per 128x128 tile
#define PSIZE ((size_t)NTRI * TSZ)   // packed S elems per batch

static __device__ __forceinline__ unsigned short f2bf(float f) {
  union { float f; unsigned u; } v; v.f = f;
  unsigned r = v.u + 0x7FFFu + ((v.u >> 16) & 1u);
  return (unsigned short)(r >> 16);
}

static __device__ __forceinline__ unsigned short f2h(float f) {
  union { _Float16 h; unsigned short u; } v; v.h = (_Float16)f; return v.u;
}

static __device__ __forceinline__ float h2f(unsigned short u) {
  union { unsigned short u; _Float16 h; } v; v.u = u; return (float)v.h;
}

static __device__ __forceinline__ bf16x8 pack8(f32x4 a, f32x4 b) {
  bf16x8 v;
  v[0]=(short)f2bf(a[0]); v[1]=(short)f2bf(a[1]);
  v[2]=(short)f2bf(a[2]); v[3]=(short)f2bf(a[3]);
  v[4]=(short)f2bf(b[0]); v[5]=(short)f2bf(b[1]);
  v[6]=(short)f2bf(b[2]); v[7]=(short)f2bf(b[3]);
  return v;
}

// row index of lower-triangle tile id (id = ti*(ti+1)/2 + tj)
static __device__ __forceinline__ int tri_row(int id) {
  int ti = (int)((sqrtf(8.f * (float)id + 1.f) - 1.f) * 0.5f);
  while ((ti + 1) * (ti + 2) / 2 <= id) ++ti;
  while (ti * (ti + 1) / 2 > id) --ti;
  return ti;
}

// ---------------- fp32 -> bf16 preconvert ----------------
__global__ __launch_bounds__(256) void conv_bf16(
    const float* __restrict__ src, unsigned short* __restrict__ dst,
    int n8, float scale)
{
  const int i = blockIdx.x * 256 + threadIdx.x;
  if (i < n8) {
    const f32x4* s = (const f32x4*)(src + (size_t)i * 8);
    f32x4 a = s[0], b = s[1];
#pragma unroll
    for (int r = 0; r < 4; ++r) { a[r] *= scale; b[r] *= scale; }
    *(bf16x8*)(dst + (size_t)i * 8) = pack8(a, b);
  }
}

// all three weights in one launch; Wq gets 1/sqrt(D) folded in
__global__ __launch_bounds__(256) void conv_w3(
    const float* __restrict__ Wq, const float* __restrict__ Wk,
    const float* __restrict__ Wv, unsigned short* __restrict__ dst)
{
  const int i = blockIdx.x * 256 + threadIdx.x;
  const int seg = i >> 17;
  const int loc = i & 131071;
  const float* src = (seg == 0) ? Wq : (seg == 1) ? Wk : Wv;
  const float scale = (seg == 0) ? 0.03125f : 1.0f;
  const f32x4* s = (const f32x4*)(src + (size_t)loc * 8);
  f32x4 a = s[0], b = s[1];
#pragma unroll
  for (int r = 0; r < 4; ++r) { a[r] *= scale; b[r] *= scale; }
  *(bf16x8*)(dst + (size_t)i * 8) = pack8(a, b);
}

// ============================================================================
// Shared sync helpers (counted-vmcnt pipeline).
// Pipeline invariant: buf p for K-tile v is (a) only read after vmcnt proves
// its loads landed in every wave + barrier, (b) only re-staged (tile v+2)
// after the barrier ending the last read of tile v.
// ============================================================================
static __device__ __forceinline__ void head_sync(bool more) {
  if (more) asm volatile("s_waitcnt vmcnt(8)" ::: "memory");
  else      asm volatile("s_waitcnt vmcnt(0)" ::: "memory");
  __builtin_amdgcn_s_barrier();
  asm volatile("" ::: "memory");
}

static __device__ __forceinline__ void tail_sync() {
  asm volatile("" ::: "memory");
  __builtin_amdgcn_s_barrier();
  asm volatile("" ::: "memory");
}

// ============================================================================
// 256x256-tile core (8 waves, BK=64). LDS 128 KiB. Swizzle: LDS(row,c) =
// G(row, c ^ sw(row)), sw(row)=((row>>2)&3)<<4 elems (both-sides involution).
// ============================================================================
static __device__ __forceinline__ void stage256(
    const unsigned short* __restrict__ Ab, const unsigned short* __restrict__ Bb,
    int lda, int ldb, unsigned short* Au, unsigned short* Bu, int tid)
{
  const int w = tid >> 6;
  const int srow = tid >> 3;
  const int scol = (tid & 7) * 8;
#pragma unroll
  for (int L = 0; L < 4; ++L) {
    const int row = L * 64 + srow;
    const int sw = ((row >> 2) & 3) << 4;
    const unsigned short* ga = Ab + (size_t)row * lda + (scol ^ sw);
    const unsigned short* gb = Bb + (size_t)row * ldb + (scol ^ sw);
    __builtin_amdgcn_global_load_lds(
        (const __attribute__((address_space(1))) void*)ga,
        (__attribute__((address_space(3))) void*)&Au[(L * 64 + w * 8) * 64], 16, 0, 0);
    __builtin_amdgcn_global_load_lds(
        (const __attribute__((address_space(1))) void*)gb,
        (__attribute__((address_space(3))) void*)&Bu[(L * 64 + w * 8) * 64], 16, 0, 0);
  }
}

static __device__ __forceinline__ void compute256(
    const unsigned short* Au, const unsigned short* Bu,
    int wr, int wc, int l15, int quad, f32x4 (&acc)[8][4])
{
  const int csw = (l15 >> 2) << 4;
  bf16x8 bfr[4][2];
#pragma unroll
  for (int fn = 0; fn < 4; ++fn)
#pragma unroll
    for (int ks = 0; ks < 2; ++ks) {
      const int row = wc * 64 + fn * 16 + l15;
      bfr[fn][ks] = *(const bf16x8*)&Bu[row * 64 + ((ks * 32 + quad * 8) ^ csw)];
    }
  __builtin_amdgcn_s_setprio(1);
#pragma unroll
  for (int h = 0; h < 2; ++h) {
    bf16x8 af[4][2];
#pragma unroll
    for (int f = 0; f < 4; ++f)
#pragma unroll
      for (int ks = 0; ks < 2; ++ks) {
        const int row = wr * 128 + h * 64 + f * 16 + l15;
        af[f][ks] = *(const bf16x8*)&Au[row * 64 + ((ks * 32 + quad * 8) ^ csw)];
      }
#pragma unroll
    for (int ks = 0; ks < 2; ++ks)
#pragma unroll
      for (int f = 0; f < 4; ++f)
#pragma unroll
        for (int fn = 0; fn < 4; ++fn)
          acc[h * 4 + f][fn] = __builtin_amdgcn_mfma_f32_16x16x32_bf16(
              af[f][ks], bfr[fn][ks], acc[h * 4 + f][fn], 0, 0, 0);
  }
  __builtin_amdgcn_s_setprio(0);
}

// ---------------- QKV GEMM, z-fused: 256 blocks x 512 thr, 48 K-tiles -------
__global__ __launch_bounds__(512, 2) void qkv_gemm3(
    const unsigned short* __restrict__ xb,
    const unsigned short* __restrict__ Wb,
    unsigned short* __restrict__ outQ)
{
  __shared__ unsigned short Au[2][256 * 64];
  __shared__ unsigned short Bu[2][256 * 64];

  const int bid = blockIdx.x;               // 256
  const int xcd = bid & 7, i = bid >> 3;
  const int mt = xcd * 8 + (i >> 2);        // A-panel locality per XCD
  const int nt = i & 3;
  const int m0 = mt * 256, n0 = nt * 256;

  const int tid = threadIdx.x;
  const int w = tid >> 6, ln = tid & 63;
  const int l15 = ln & 15, quad = ln >> 4;
  const int wr = w >> 2, wc = w & 3;

  const unsigned short* Ab0 = xb + (size_t)m0 * DIM;

  f32x4 acc[8][4] = {};

  auto stage_v = [&](int v, int p) {
    const int z = v >> 4, k0 = (v & 15) * 64;
    const unsigned short* Bz = Wb + (size_t)z * (DIM * DIM) + (size_t)n0 * DIM;
    stage256(Ab0 + k0, Bz + k0, DIM, DIM, Au[p], Bu[p], tid);
  };

  stage_v(0, 0);
  stage_v(1, 1);

#pragma unroll 1
  for (int v = 0; v < 48; ++v) {
    const int p = v & 1;
    head_sync(v + 1 < 48);
    compute256(Au[p], Bu[p], wr, wc, l15, quad, acc);
    tail_sync();
    if (v + 2 < 48) stage_v(v + 2, p);

    if ((v & 15) == 15) {
      const int z = v >> 4;
      unsigned short* outb = outQ + (size_t)z * ((size_t)MTOT * DIM);
      if (z < 2) {
#pragma unroll
        for (int fm = 0; fm < 8; ++fm)
#pragma unroll
          for (int fn = 0; fn < 4; ++fn) {
            const int m = m0 + wr * 128 + fm * 16 + quad * 4;
            const int e = n0 + wc * 64 + fn * 16 + l15;
            unsigned short* pp = outb + (size_t)m * DIM + e;
#pragma unroll
            for (int r = 0; r < 4; ++r) pp[(size_t)r * DIM] = f2bf(acc[fm][fn][r]);
          }
      } else {
#pragma unroll
        for (int fm = 0; fm < 8; ++fm)
#pragma unroll
          for (int fn = 0; fn < 4; ++fn) {
            const int m = m0 + wr * 128 + fm * 16 + quad * 4;   // s index
            const int e = n0 + wc * 64 + fn * 16 + l15;         // dim index
            const int bb = m >> 12, ss = m & 4095;
            u16x4 v4;
#pragma unroll
            for (int r = 0; r < 4; ++r) v4[r] = f2bf(acc[fm][fn][r]);
            *(u16x4*)(outb + ((size_t)bb * DIM + e) * SEQ + ss) = v4;
          }
      }
#pragma unroll
      for (int fm = 0; fm < 8; ++fm)
#pragma unroll
        for (int fn = 0; fn < 4; ++fn) acc[fm][fn] = (f32x4){0.f, 0.f, 0.f, 0.f};
    }
  }
}

// ============================================================================
// 128x128-tile core (4 waves, BK=64, counted-vmcnt double buffer, swizzled).
// LDS 64 KiB -> 2 blocks/CU resident.
// ============================================================================
static __device__ __forceinline__ void stage128(
    const unsigned short* __restrict__ Ab, int lda,
    const unsigned short* __restrict__ Bb, int ldb,
    unsigned short* Al, unsigned short* Bl, int tid)
{
  const int wv = tid >> 6, ln = tid & 63;
  const int lrow = ln >> 3, lcol = (ln & 7) * 8;
#pragma unroll
  for (int r = 0; r < 4; ++r) {
    const int row = (wv * 4 + r) * 8 + lrow;
    const int sw = ((row >> 2) & 3) << 4;
    __builtin_amdgcn_global_load_lds(
        (const __attribute__((address_space(1))) void*)(Ab + (size_t)row * lda + (lcol ^ sw)),
        (__attribute__((address_space(3))) void*)&Al[(wv * 4 + r) * 512], 16, 0, 0);
    __builtin_amdgcn_global_load_lds(
        (const __attribute__((address_space(1))) void*)(Bb + (size_t)row * ldb + (lcol ^ sw)),
        (__attribute__((address_space(3))) void*)&Bl[(wv * 4 + r) * 512], 16, 0, 0);
  }
}

static __device__ __forceinline__ void compute128(
    const unsigned short* Al, const unsigned short* Bl,
    int mw, int nw, int l15, int quad, f32x4 (&acc)[4][4])
{
  const int csw = (l15 >> 2) << 4;
#pragma unroll
  for (int ks = 0; ks < 2; ++ks) {
    bf16x8 af[4], bfr[4];
#pragma unroll
    for (int i = 0; i < 4; ++i) {
      af[i]  = *(const bf16x8*)&Al[(mw * 64 + i * 16 + l15) * 64 + ((ks * 32 + quad * 8) ^ csw)];
      bfr[i] = *(const bf16x8*)&Bl[(nw * 64 + i * 16 + l15) * 64 + ((ks * 32 + quad * 8) ^ csw)];
    }
    __builtin_amdgcn_s_setprio(1);
#pragma unroll
    for (int mi = 0; mi < 4; ++mi)
#pragma unroll
      for (int ni = 0; ni < 4; ++ni)
        acc[mi][ni] = __builtin_amdgcn_mfma_f32_16x16x32_bf16(af[mi], bfr[ni], acc[mi][ni], 0, 0, 0);
    __builtin_amdgcn_s_setprio(0);
  }
}

// pipelined 128x128 GEMM over nt K-tiles of 64
static __device__ __forceinline__ void gemm128_pipe(
    const unsigned short* __restrict__ Ab, int lda,
    const unsigned short* __restrict__ Bb, int ldb, int nt,
    unsigned short (*Al)[128 * 64], unsigned short (*Bl)[128 * 64],
    int tid, int mw, int nw, int l15, int quad, f32x4 (&acc)[4][4])
{
  stage128(Ab, lda, Bb, ldb, Al[0], Bl[0], tid);
  if (nt > 1) stage128(Ab + 64, lda, Bb + 64, ldb, Al[1], Bl[1], tid);
#pragma unroll 1
  for (int v = 0; v < nt; ++v) {
    const int p = v & 1;
    head_sync(v + 1 < nt);
    compute128(Al[p], Bl[p], mw, nw, l15, quad, acc);
    tail_sync();
    if (v + 2 < nt)
      stage128(Ab + (v + 2) * 64, lda, Bb + (v + 2) * 64, ldb, Al[p], Bl[p], tid);
  }
}

// ---------------- S = Q K^T, 128-granular causal tiles, packed f16 ----------
// 1056 blocks = 2 batches x 528 tri tiles, uniform work (K=1024 each).
__global__ __launch_bounds__(256) void qk_gemm_p(
    const unsigned short* __restrict__ Q,
    const unsigned short* __restrict__ K,
    unsigned short* __restrict__ Sp)
{
  __shared__ unsigned short Al[2][128 * 64];
  __shared__ unsigned short Bl[2][128 * 64];

  const int bid = blockIdx.x;                 // 1056
  const int item = (bid & 7) * 132 + (bid >> 3);
  const int bsel = item >= NTRI;
  const int id = item - (bsel ? NTRI : 0);
  const int ti = tri_row(id);
  const int tj = id - ti * (ti + 1) / 2;

  const unsigned short* Qb = Q + (size_t)bsel * SEQ * DIM;
  const unsigned short* Kb = K + (size_t)bsel * SEQ * DIM;
  unsigned short* Sb = Sp + (size_t)bsel * PSIZE;

  const int tid = threadIdx.x, ln = tid & 63, wv = tid >> 6;
  const int l15 = ln & 15, quad = ln >> 4;
  const int mw = wv >> 1, nw = wv & 1;

  f32x4 acc[4][4] = {};
  gemm128_pipe(Qb + (size_t)(ti * 128) * DIM, DIM,
               Kb + (size_t)(tj * 128) * DIM, DIM, DIM / 64,
               Al, Bl, tid, mw, nw, l15, quad, acc);

  const int Lt = (ti + 1) << 7;
  unsigned short* base = Sb + (size_t)(ti * (ti + 1) / 2) * TSZ;
#pragma unroll
  for (int mi = 0; mi < 4; ++mi)
#pragma unroll
    for (int ni = 0; ni < 4; ++ni) {
      const int mloc = mw * 64 + mi * 16 + quad * 4;       // row within tile
      const int col  = tj * 128 + nw * 64 + ni * 16 + l15; // global key col
      unsigned short* p = base + (size_t)mloc * Lt + col;
#pragma unroll
      for (int r = 0; r < 4; ++r) p[(size_t)r * Lt] = f2h(acc[mi][ni][r]);
    }
}

// ---------------- row softmax on packed S: f16 in, normalized bf16 out ------
__global__ __launch_bounds__(256) void sm_rows_p(unsigned short* __restrict__ Sp)
{
  const int bid = blockIdx.x;
  const int bsel = bid >> 12;
  const int r = bid & 4095;
  const int ti = r >> 7, ri = r & 127;
  const int Lt = (ti + 1) << 7;
  const int len = r + 1;
  unsigned short* row = Sp + (size_t)bsel * PSIZE +
                        (size_t)(ti * (ti + 1) / 2) * TSZ + (size_t)ri * Lt;
  const int t = threadIdx.x;
  __shared__ float red[8];

  float v[16];
#pragma unroll
  for (int it = 0; it < 2; ++it) {
    const int c = t * 8 + it * 2048;
    if (c < Lt) {
      u16x8 h = *(const u16x8*)(row + c);
#pragma unroll
      for (int i = 0; i < 8; ++i)
        v[it * 8 + i] = (c + i < len) ? h2f(h[i]) : -1e30f;
    } else {
#pragma unroll
      for (int i = 0; i < 8; ++i) v[it * 8 + i] = -1e30f;
    }
  }

  float mx = v[0];
#pragma unroll
  for (int i = 1; i < 16; ++i) mx = fmaxf(mx, v[i]);
#pragma unroll
  for (int off = 1; off < 64; off <<= 1) mx = fmaxf(mx, __shfl_xor(mx, off));
  if ((t & 63) == 0) red[t >> 6] = mx;
  __syncthreads();
  mx = fmaxf(fmaxf(red[0], red[1]), fmaxf(red[2], red[3]));

  float p[16];
  float sm = 0.f;
#pragma unroll
  for (int it = 0; it < 2; ++it) {
    const int c = t * 8 + it * 2048;
#pragma unroll
    for (int i = 0; i < 8; ++i) {
      const int k = it * 8 + i;
      p[k] = (c + i < len) ? __expf(v[k] - mx) : 0.f;
      sm += p[k];
    }
  }
#pragma unroll
  for (int off = 1; off < 64; off <<= 1) sm += __shfl_xor(sm, off);
  if ((t & 63) == 0) red[4 + (t >> 6)] = sm;
  __syncthreads();
  const float inv = 1.f / (red[4] + red[5] + red[6] + red[7]);

#pragma unroll
  for (int it = 0; it < 2; ++it) {
    const int c = t * 8 + it * 2048;
    if (c < Lt) {
      u16x8 o;
#pragma unroll
      for (int i = 0; i < 8; ++i) o[i] = f2bf(p[it * 8 + i] * inv);
      *(u16x8*)(row + c) = o;
    }
  }
}

// ---------------- O = P * V on packed S -------------------------------------
// 512 blocks = 2b x 8d x 32 ti. Blocks j and j+256 have complementary ti
// (work (ti+1) + (32-ti) = 33) -> round-robin dispatch pairs them per CU.
// 64 KiB LDS -> both blocks resident.
__global__ __launch_bounds__(256) void pv_gemm_p(
    const unsigned short* __restrict__ Sp,
    const unsigned short* __restrict__ Vt,
    float* __restrict__ Ob)
{
  __shared__ unsigned short Al[2][128 * 64];
  __shared__ unsigned short Bl[2][128 * 64];

  const int bid = blockIdx.x;                 // 512
  const int d = bid & 7;
  const int rr_ = bid >> 3;                   // 0..63
  const int b = rr_ & 1;
  const int q = rr_ >> 1;                     // 0..31
  const int ti = (q & 16) ? (31 - (q & 15)) : q;
  const int Lt = (ti + 1) << 7;

  const unsigned short* Sb = Sp + (size_t)b * PSIZE + (size_t)(ti * (ti + 1) / 2) * TSZ;
  const unsigned short* Vb = Vt + (size_t)b * ((size_t)DIM * SEQ) +
                             (size_t)(d * 128) * SEQ;
  float* Outb = Ob + (size_t)b * ((size_t)SEQ * DIM);

  const int tid = threadIdx.x, ln = tid & 63, wv = tid >> 6;
  const int l15 = ln & 15, quad = ln >> 4;
  const int mw = wv >> 1, nw = wv & 1;

  f32x4 acc[4][4] = {};
  gemm128_pipe(Sb, Lt, Vb, SEQ, Lt / 64, Al, Bl, tid, mw, nw, l15, quad, acc);

#pragma unroll
  for (int mi = 0; mi < 4; ++mi)
#pragma unroll
    for (int ni = 0; ni < 4; ++ni) {
      const int m = ti * 128 + mw * 64 + mi * 16 + quad * 4;
      const int e = d * 128 + nw * 64 + ni * 16 + l15;
      float* pp = Outb + (size_t)m * DIM + e;
#pragma unroll
      for (int r = 0; r < 4; ++r) pp[(size_t)r * DIM] = acc[mi][ni][r];
    }
}

extern "C" void kernel_launch(void* const* d_in, const int* in_sizes, int n_in,
                              void* d_out, int out_size, void* d_ws, size_t ws_size,
                              hipStream_t stream) {
  const float* x  = (const float*)d_in[0];
  const float* Wq = (const float*)d_in[1];
  const float* Wk = (const float*)d_in[2];
  const float* Wv = (const float*)d_in[3];
  float* out = (float*)d_out;

  // ws layout (134.25 MB):
  //   [0,38MB):    xb (bf16 x, 32MB) + Wb (bf16 weights, 6MB)
  //                -> after qkv: 128-packed causal S, 2 batches (2 x 16.5MB)
  //   [38,70MB):   Q bf16   [70,102MB): K bf16   [102,134MB): Vt bf16
  char* wsb = (char*)d_ws;
  unsigned short* xb = (unsigned short*)wsb;
  unsigned short* Wb = (unsigned short*)(wsb + (32u << 20));
  unsigned short* Qb = (unsigned short*)(wsb + (38u << 20));
  unsigned short* Sp = xb;

  conv_bf16<<<8192, 256, 0, stream>>>(x, xb, 2097152, 1.0f);
  conv_w3<<<1536, 256, 0, stream>>>(Wq, Wk, Wv, Wb);

  qkv_gemm3<<<256, 512, 0, stream>>>(xb, Wb, Qb);

  const size_t n = (size_t)MTOT * DIM;
  for (int p = 0; p < 2; ++p) {
    const unsigned short* Qp  = Qb + (size_t)p * 2 * SEQ * DIM;
    const unsigned short* Kp  = Qb + n + (size_t)p * 2 * SEQ * DIM;
    const unsigned short* Vtp = Qb + 2 * n + (size_t)p * 2 * DIM * SEQ;
    float* Op = out + (size_t)p * 2 * SEQ * DIM;

    qk_gemm_p<<<1056, 256, 0, stream>>>(Qp, Kp, Sp);
    sm_rows_p<<<8192, 256, 0, stream>>>(Sp);
    pv_gemm_p<<<512, 256, 0, stream>>>(Sp, Vtp, Op);
  }
}